// Round 1
// baseline (9963.416 us; speedup 1.0000x reference)
//
#include <hip/hip_runtime.h>
#include <hip/hip_bf16.h>

typedef __attribute__((ext_vector_type(8))) _Float16 f16x8;
typedef __attribute__((ext_vector_type(4))) float floatx4;

#define T_SEQ 512
#define B_SZ  64
#define I_SZ  512
#define H_SZ  1024
#define NC    3072          // output cols of x-projection: [r(1024) | z(1024) | h(1024)]
#define NWG   64            // persistent workgroups
#define JS    16            // H_SZ / NWG columns per WG

// ---------------- workspace layout (bytes) ----------------
// xproj fp16 [B*T][3072]                 : 201,326,592
// h master fp32 [B][H]                   : 262,144
// h fp16 [B][H]                          : 131,072
// rh fp16 [B][H]                         : 131,072
// flags  [NWG] u32                       : 256
static const size_t XPROJ_BYTES = (size_t)B_SZ * T_SEQ * NC * 2;
static const size_t HM_OFF  = XPROJ_BYTES;
static const size_t H16_OFF = HM_OFF + (size_t)B_SZ * H_SZ * 4;
static const size_t RH_OFF  = H16_OFF + (size_t)B_SZ * H_SZ * 2;
static const size_t FLG_OFF = RH_OFF + (size_t)B_SZ * H_SZ * 2;

__device__ __forceinline__ f16x8 cvt8(float4 a, float4 b) {
  f16x8 v;
  v[0] = (_Float16)a.x; v[1] = (_Float16)a.y; v[2] = (_Float16)a.z; v[3] = (_Float16)a.w;
  v[4] = (_Float16)b.x; v[5] = (_Float16)b.y; v[6] = (_Float16)b.z; v[7] = (_Float16)b.w;
  return v;
}

// ---------------- init: h master + h fp16 + flags ----------------
__global__ void init_h_kernel(const float* __restrict__ h0,
                              float* __restrict__ hm,
                              _Float16* __restrict__ h16,
                              unsigned* __restrict__ flags) {
  int i = blockIdx.x * blockDim.x + threadIdx.x;
  if (i < B_SZ * H_SZ) {
    float v = h0[i];
    hm[i]  = v;
    h16[i] = (_Float16)v;
  }
  if (blockIdx.x == 0 && threadIdx.x < NWG) flags[threadIdx.x] = 0u;
}

// ---------------- pre-GEMM: xproj = x @ Wx^T + bias (fp16 out) ----------------
// A [32768,512] fp32 -> fp16 staged; B rows = [W_rz rows 0..2047 | W_h rows 0..1023],
// x-part columns k=0..511. BM=BN=128, BK=32, 256 threads, 16x16x32 f16 MFMA.
__global__ __launch_bounds__(256) void pregemm_kernel(
    const float* __restrict__ X, const float* __restrict__ Wrz,
    const float* __restrict__ Wh, const float* __restrict__ brz,
    const float* __restrict__ bh, _Float16* __restrict__ xproj) {
  __shared__ __align__(16) char smem[128 * 64 * 2];   // As | Bs, 32 halves (64B) per row
  char* Asb = smem;
  char* Bsb = smem + 128 * 64;
  const int tid = threadIdx.x;
  const int w = tid >> 6, l = tid & 63;
  const int lg = l >> 4, ln = l & 15;
  const int wm = w >> 1, wn = w & 1;
  const int m0 = blockIdx.x * 128;
  const int n0 = blockIdx.y * 128;
  const int rs = tid >> 1;          // staging row 0..127
  const int ks = (tid & 1) * 16;    // staging k-seg (floats)

  floatx4 acc[4][4];
#pragma unroll
  for (int i = 0; i < 4; i++)
#pragma unroll
    for (int j = 0; j < 4; j++) acc[i][j] = (floatx4){0.f, 0.f, 0.f, 0.f};

  const float* garow = X + (size_t)(m0 + rs) * I_SZ + ks;
  const int nrow = n0 + rs;
  const float* gbrow = (nrow < 2048) ? (Wrz + (size_t)nrow * 1536 + ks)
                                     : (Wh + (size_t)(nrow - 2048) * 1536 + ks);
  for (int kt = 0; kt < I_SZ; kt += 32) {
    float4 a0 = ((const float4*)(garow + kt))[0];
    float4 a1 = ((const float4*)(garow + kt))[1];
    float4 a2 = ((const float4*)(garow + kt))[2];
    float4 a3 = ((const float4*)(garow + kt))[3];
    float4 b0 = ((const float4*)(gbrow + kt))[0];
    float4 b1 = ((const float4*)(gbrow + kt))[1];
    float4 b2 = ((const float4*)(gbrow + kt))[2];
    float4 b3 = ((const float4*)(gbrow + kt))[3];
    __syncthreads();   // previous iter's LDS reads done
    {
      int c0 = ks >> 3;  // 16B chunk index (0 or 2)
      f16x8* wp = (f16x8*)(Asb + rs * 64);
      wp[(c0)     ^ (rs & 3)] = cvt8(a0, a1);
      wp[(c0 + 1) ^ (rs & 3)] = cvt8(a2, a3);
      f16x8* wq = (f16x8*)(Bsb + rs * 64);
      wq[(c0)     ^ (rs & 3)] = cvt8(b0, b1);
      wq[(c0 + 1) ^ (rs & 3)] = cvt8(b2, b3);
    }
    __syncthreads();   // staging visible
    f16x8 af[4], bf[4];
#pragma unroll
    for (int i = 0; i < 4; i++) {
      int ra = wm * 64 + i * 16 + ln;
      af[i] = ((const f16x8*)(Asb + ra * 64))[lg ^ (ra & 3)];
      int rb = wn * 64 + i * 16 + ln;
      bf[i] = ((const f16x8*)(Bsb + rb * 64))[lg ^ (rb & 3)];
    }
#pragma unroll
    for (int i = 0; i < 4; i++)
#pragma unroll
      for (int j = 0; j < 4; j++)
        acc[i][j] = __builtin_amdgcn_mfma_f32_16x16x32_f16(af[i], bf[j], acc[i][j], 0, 0, 0);
  }
  // epilogue: add bias (update-bias folded into z cols), store fp16
#pragma unroll
  for (int j = 0; j < 4; j++) {
    int n = n0 + wn * 64 + j * 16 + ln;
    float bias = (n < 2048) ? (brz[n] + ((n >= 1024) ? 1.0f : 0.0f)) : bh[n - 2048];
#pragma unroll
    for (int i = 0; i < 4; i++) {
      int mrow = m0 + wm * 64 + i * 16 + 4 * lg;
#pragma unroll
      for (int q = 0; q < 4; q++) {
        xproj[(size_t)(mrow + q) * NC + n] = (_Float16)(acc[i][j][q] + bias);
      }
    }
  }
}

// ---------------- grid barrier (monotone flags; wave0 polls, others spin LDS) ----------------
__device__ __forceinline__ void wg_barrier(unsigned* flags, unsigned target,
                                           volatile unsigned* done) {
  __syncthreads();  // all WG work issued & drained (compiler emits vmcnt(0) before s_barrier)
  const int tid = threadIdx.x;
  if (tid < 64) {
    if (tid == 0) {
      __threadfence();  // agent-scope release: L2 writeback so remote XCDs see our data
      __hip_atomic_store(&flags[blockIdx.x], target, __ATOMIC_RELAXED,
                         __HIP_MEMORY_SCOPE_AGENT);
    }
    unsigned v;
    do {
      v = __hip_atomic_load(&flags[tid], __ATOMIC_RELAXED, __HIP_MEMORY_SCOPE_AGENT);
    } while (__all((int)(v >= target)) == 0);
    __threadfence();  // agent-scope acquire: invalidate L1/L2 before reading remote data
    if (tid == 0) *done = target;
  } else {
    while (*done < target) { }
  }
}

// ---------------- persistent GRU recurrence ----------------
// WG g owns H-columns [16g, 16g+16). LDS holds (for all 512 steps):
//   wA rows 0..15  = W_rz[16g + n][512..1535]        (r rows)
//   wA rows 16..31 = W_rz[1024 + 16g + n][512..1535] (z rows)
//   wB rows 0..15  = W_h [16g + n][512..1535]
// Per step: phase A: rz = h16 @ wA^T (+staged x-part) -> r,z ; rh = r*h (fp32 h)
//           barrier ; phase B: hhat = rh16 @ wB^T (+staged) ; h_new ; barrier.
__global__ __launch_bounds__(256) void gru_persistent_kernel(
    const float* __restrict__ Wrz, const float* __restrict__ Wh,
    const _Float16* __restrict__ xproj, float* __restrict__ Y,
    float* __restrict__ hm, _Float16* __restrict__ h16,
    _Float16* __restrict__ rh16, unsigned* __restrict__ flags) {
  __shared__ __align__(16) char smem[98304];  // 32*2048 (wA) + 16*2048 (wB)
  __shared__ unsigned bar_done;
  const int g = blockIdx.x;
  const int tid = threadIdx.x;
  const int w = tid >> 6, l = tid & 63;
  const int lg = l >> 4, ln = l & 15;

  if (tid == 0) bar_done = 0u;

  // load + convert weights into LDS (XOR-swizzled 16B chunks: chunk' = c ^ (row&7))
  for (int it = tid; it < 48 * 128; it += 256) {
    int r = it >> 7;
    int c = it & 127;
    const float* src;
    int n; size_t base;
    if (r < 32) {
      int gr = (r < 16) ? (JS * g + r) : (1024 + JS * g + (r - 16));
      src = Wrz + (size_t)gr * 1536 + 512 + c * 8;
      n = r; base = 0;
    } else {
      int gr = JS * g + (r - 32);
      src = Wh + (size_t)gr * 1536 + 512 + c * 8;
      n = r - 32; base = 65536;
    }
    float4 f0 = ((const float4*)src)[0];
    float4 f1 = ((const float4*)src)[1];
    ((f16x8*)(smem + base + (size_t)n * 2048))[c ^ (n & 7)] = cvt8(f0, f1);
  }
  __syncthreads();

  const int jg = JS * g + ln;  // global H-column this lane owns
  const int sw = ln & 7;
  const f16x8* bpr = (const f16x8*)(smem + (size_t)ln * 2048);
  const f16x8* bpz = (const f16x8*)(smem + (size_t)(16 + ln) * 2048);
  const f16x8* bph = (const f16x8*)(smem + 65536 + (size_t)ln * 2048);

  unsigned bar = 0;
  float zq[4], hmv[4];

  for (int t = 0; t < T_SEQ; ++t) {
    // prefetch staged x-projections (r,z,h) + fp32 h slice early; consumed after MFMA loops
    float xr[4], xz[4], xh[4];
#pragma unroll
    for (int q = 0; q < 4; q++) {
      int b = 16 * w + 4 * lg + q;
      size_t row = ((size_t)b * T_SEQ + t) * NC;
      xr[q] = (float)xproj[row + jg];
      xz[q] = (float)xproj[row + 1024 + jg];
      xh[q] = (float)xproj[row + 2048 + jg];
      hmv[q] = hm[b * H_SZ + jg];
    }
    // ---------------- phase A: r,z ----------------
    {
      floatx4 a00 = {0,0,0,0}, a01 = {0,0,0,0}, a10 = {0,0,0,0}, a11 = {0,0,0,0};
      const f16x8* ap = (const f16x8*)(h16 + (16 * w + ln) * H_SZ + 8 * lg);
#pragma unroll
      for (int ki = 0; ki < 32; ++ki) {
        f16x8 a  = ap[4 * ki];
        f16x8 br = bpr[(4 * ki + lg) ^ sw];
        f16x8 bz = bpz[(4 * ki + lg) ^ sw];
        if (ki & 1) {
          a01 = __builtin_amdgcn_mfma_f32_16x16x32_f16(a, br, a01, 0, 0, 0);
          a11 = __builtin_amdgcn_mfma_f32_16x16x32_f16(a, bz, a11, 0, 0, 0);
        } else {
          a00 = __builtin_amdgcn_mfma_f32_16x16x32_f16(a, br, a00, 0, 0, 0);
          a10 = __builtin_amdgcn_mfma_f32_16x16x32_f16(a, bz, a10, 0, 0, 0);
        }
      }
      floatx4 Dr = a00 + a01, Dz = a10 + a11;
#pragma unroll
      for (int q = 0; q < 4; q++) {
        int b = 16 * w + 4 * lg + q;
        float rr = 1.f / (1.f + __expf(-(Dr[q] + xr[q])));
        zq[q]    = 1.f / (1.f + __expf(-(Dz[q] + xz[q])));
        rh16[b * H_SZ + jg] = (_Float16)(rr * hmv[q]);
      }
    }
    ++bar; wg_barrier(flags, bar, &bar_done);
    // ---------------- phase B: hhat, h_new ----------------
    {
      floatx4 a0 = {0,0,0,0}, a1 = {0,0,0,0};
      const f16x8* ap = (const f16x8*)(rh16 + (16 * w + ln) * H_SZ + 8 * lg);
#pragma unroll
      for (int ki = 0; ki < 32; ++ki) {
        f16x8 a = ap[4 * ki];
        f16x8 bh8 = bph[(4 * ki + lg) ^ sw];
        if (ki & 1) a1 = __builtin_amdgcn_mfma_f32_16x16x32_f16(a, bh8, a1, 0, 0, 0);
        else        a0 = __builtin_amdgcn_mfma_f32_16x16x32_f16(a, bh8, a0, 0, 0, 0);
      }
      floatx4 Dh = a0 + a1;
#pragma unroll
      for (int q = 0; q < 4; q++) {
        int b = 16 * w + 4 * lg + q;
        float hhat = tanhf(Dh[q] + xh[q]);
        float hn = zq[q] * hmv[q] + (1.f - zq[q]) * hhat;
        Y[((size_t)b * T_SEQ + t) * H_SZ + jg] = hn;
        hm[b * H_SZ + jg] = hn;
        h16[b * H_SZ + jg] = (_Float16)hn;
      }
    }
    ++bar; wg_barrier(flags, bar, &bar_done);
  }
}

// ---------------- launch ----------------
extern "C" void kernel_launch(void* const* d_in, const int* in_sizes, int n_in,
                              void* d_out, int out_size, void* d_ws, size_t ws_size,
                              hipStream_t stream) {
  const float* X   = (const float*)d_in[0];
  const float* h0  = (const float*)d_in[1];
  const float* Wrz = (const float*)d_in[2];
  const float* brz = (const float*)d_in[3];
  const float* Wh  = (const float*)d_in[4];
  const float* bh  = (const float*)d_in[5];
  float* Y = (float*)d_out;
  char* ws = (char*)d_ws;

  _Float16* xproj = (_Float16*)(ws);
  float*    hm    = (float*)(ws + HM_OFF);
  _Float16* h16   = (_Float16*)(ws + H16_OFF);
  _Float16* rh16  = (_Float16*)(ws + RH_OFF);
  unsigned* flags = (unsigned*)(ws + FLG_OFF);

  hipLaunchKernelGGL(init_h_kernel, dim3(256), dim3(256), 0, stream, h0, hm, h16, flags);
  hipLaunchKernelGGL(pregemm_kernel, dim3(256, 24), dim3(256), 0, stream,
                     X, Wrz, Wh, brz, bh, xproj);

  void* kargs[] = { (void*)&Wrz, (void*)&Wh, (void*)&xproj, (void*)&Y,
                    (void*)&hm, (void*)&h16, (void*)&rh16, (void*)&flags };
  hipLaunchCooperativeKernel((void*)gru_persistent_kernel, dim3(NWG), dim3(256),
                             kargs, 0, stream);
}